// Round 9
// baseline (91.700 us; speedup 1.0000x reference)
//
#include <hip/hip_runtime.h>

#define B_      2
#define C_      256
#define H_      96
#define W_      96
#define HW_     (H_ * W_)
#define P_      7
#define PP_     (P_ * P_)
#define NROIS_  512
#define SCALE_  0.0625f
#define TSTD_   0.1f

#define NGROUP_ 8                       // channel groups
#define GC_     (C_ / NGROUP_)          // 32 channels per group

typedef float vf4 __attribute__((ext_vector_type(4)));   // native vec for nt builtins

// f32 -> bf16 (round-to-nearest-even), as raw bits
__device__ __forceinline__ unsigned f2bf(float f) {
    union { float f; unsigned u; } x; x.f = f;
    return (x.u + 0x7fffu + ((x.u >> 16) & 1u)) >> 16;
}
__device__ __forceinline__ float bf_lo(unsigned u) {
    union { unsigned i; float f; } x; x.i = u << 16; return x.f;
}
__device__ __forceinline__ float bf_hi(unsigned u) {
    union { unsigned i; float f; } x; x.i = u & 0xffff0000u; return x.f;
}
// 1D bilinear hat weight
__device__ __forceinline__ float hat(float d) { return fmaxf(0.0f, 1.0f - fabsf(d)); }

// ---------------------------------------------------------------------------
// Pass 1: f32 CHW -> bf16 group-planar [b][g][HW][32ch]. (R8, unchanged)
// ---------------------------------------------------------------------------
__global__ __launch_bounds__(256) void nchw_to_gp_bf16(const float* __restrict__ in,
                                                       ushort* __restrict__ out) {
    __shared__ float tile[32][36];          // [ch][px], stride 36: b128-aligned
    const int b   = blockIdx.z;
    const int g   = blockIdx.x & (NGROUP_ - 1);
    const int p0  = (blockIdx.x >> 3) * 32;
    const int c0  = g * 32;
    const int tid = threadIdx.x;

    const float* src = in + (size_t)b * (C_ * HW_);
    ushort*      dst = out + ((size_t)(b * NGROUP_ + g) * HW_) * GC_;

    {
        const int cr = tid >> 3;
        const int pq = (tid & 7) * 4;
        const vf4 v = __builtin_nontemporal_load(
            (const vf4*)&src[(size_t)(c0 + cr) * HW_ + p0 + pq]);
        *(vf4*)&tile[cr][pq] = v;
    }
    __syncthreads();
    {
        const int p  = tid >> 3;
        const int cq = (tid & 7) * 4;
        uint2 o;
        o.x = f2bf(tile[cq + 0][p]) | (f2bf(tile[cq + 1][p]) << 16);
        o.y = f2bf(tile[cq + 2][p]) | (f2bf(tile[cq + 3][p]) << 16);
        *(uint2*)&((unsigned*)dst)[(size_t)(p0 + p) * (GC_ / 2) + (cq >> 1)] = o;
    }
}

// ---------------------------------------------------------------------------
// Pass 2: separable-stencil pooling.  The 2x2 samples x 4 bilinear corners
// (16 gathers) collapse to one separable stencil over a <=5x5 pixel box:
//   sum_{sa,sb} valid * wy_sa(yy) * wx_sb(xx) = WY[yy] * WX[xx],
//   WX[k] = sum_sb validw_sb * hat(wc_sb - (x_lo+k))   (hat = bilinear 1D)
// Typical box is 3x3 -> 9 loads (was 16): ~35% fewer L1 line-requests, the
// measured limiter.  Core 3x3 unconditional+hoisted (MLP 9); slots 3/4 only
// when their weight > 0 (sub-spacing > ~1 px).  Core may read <=2 px past a
// plane with weight exactly 0.0f -- stays inside the 256 MiB ws, finite data.
// ---------------------------------------------------------------------------
__global__ __launch_bounds__(256, 4) void dpsroi_pool8(const ushort* __restrict__ feat,
                                                       const float* __restrict__ rois,
                                                       const float* __restrict__ trans,
                                                       float* __restrict__ out) {
    __shared__ float sout[GC_ * PP_];       // 32*49*4 = 6272 B, global layout

    const int blk = blockIdx.x;
    const int g   = blk & (NGROUP_ - 1);
    const int n   = blk >> 3;
    const int tid = threadIdx.x;
    const int bin = tid >> 2;               // 0..63 (49 active)
    const int ch0 = (tid & 3) * 8;          // 8 channels per lane

    // ROI geometry (block-uniform)
    const int   broi = (int)rois[n * 5 + 0];
    const float x1 = rintf(rois[n * 5 + 1]) * SCALE_ - 0.5f;
    const float y1 = rintf(rois[n * 5 + 2]) * SCALE_ - 0.5f;
    const float x2 = (rintf(rois[n * 5 + 3]) + 1.0f) * SCALE_ - 0.5f;
    const float y2 = (rintf(rois[n * 5 + 4]) + 1.0f) * SCALE_ - 0.5f;
    const float rw = fmaxf(x2 - x1, 0.1f);
    const float rh = fmaxf(y2 - y1, 0.1f);
    const float bin_w = rw * (1.0f / 7.0f);
    const float bin_h = rh * (1.0f / 7.0f);
    const float sub_w = bin_w * 0.5f;
    const float sub_h = bin_h * 0.5f;

    const ushort* fb = feat + ((size_t)(broi * NGROUP_ + g) * HW_) * GC_ + ch0;

    if (bin < PP_) {
        const int pi = bin / P_;
        const int pj = bin - pi * P_;
        const float tx = trans[((n * 2 + 0) * P_ + pi) * P_ + pj] * TSTD_;
        const float ty = trans[((n * 2 + 1) * P_ + pi) * P_ + pj] * TSTD_;
        const float w0 = (float)pj * bin_w + x1 + tx * rw;
        const float h0 = (float)pi * bin_h + y1 + ty * rh;
        const float w1 = w0 + sub_w;
        const float h1 = h0 + sub_h;

        // validity on unclipped coords; clamp for sampling
        const int vw0 = (w0 >= -0.5f) & (w0 <= (float)W_ - 0.5f);
        const int vw1 = (w1 >= -0.5f) & (w1 <= (float)W_ - 0.5f);
        const int vh0 = (h0 >= -0.5f) & (h0 <= (float)H_ - 0.5f);
        const int vh1 = (h1 >= -0.5f) & (h1 <= (float)H_ - 0.5f);
        const int cnt = (vw0 + vw1) * (vh0 + vh1);

        const float wc0 = fminf(fmaxf(w0, 0.0f), (float)(W_ - 1));
        const float wc1 = fminf(fmaxf(w1, 0.0f), (float)(W_ - 1));
        const float hc0 = fminf(fmaxf(h0, 0.0f), (float)(H_ - 1));
        const float hc1 = fminf(fmaxf(h1, 0.0f), (float)(H_ - 1));

        const int x_lo = (int)floorf(wc0);
        const int y_lo = (int)floorf(hc0);
        const float fvw0 = (float)vw0, fvw1 = (float)vw1;
        const float fvh0 = (float)vh0, fvh1 = (float)vh1;

        float WX[5], WY[5];
#pragma unroll
        for (int k = 0; k < 5; ++k) {
            const float xx = (float)(x_lo + k);
            const float yy = (float)(y_lo + k);
            WX[k] = fvw0 * hat(wc0 - xx) + fvw1 * hat(wc1 - xx);
            WY[k] = fvh0 * hat(hc0 - yy) + fvh1 * hat(hc1 - yy);
        }

        const int base = y_lo * W_ + x_lo;
        float acc[8] = {0.f, 0.f, 0.f, 0.f, 0.f, 0.f, 0.f, 0.f};

#define ACCUM(J, K, V)                                                         \
        {                                                                      \
            const float wgt = WY[J] * WX[K];                                   \
            acc[0] += wgt * bf_lo((V).x);  acc[1] += wgt * bf_hi((V).x);       \
            acc[2] += wgt * bf_lo((V).y);  acc[3] += wgt * bf_hi((V).y);       \
            acc[4] += wgt * bf_lo((V).z);  acc[5] += wgt * bf_hi((V).z);       \
            acc[6] += wgt * bf_lo((V).w);  acc[7] += wgt * bf_hi((V).w);       \
        }
#define LOADPX(J, K) (*(const uint4*)(fb + (size_t)(base + (J) * W_ + (K)) * GC_))

        // ---- core 3x3: unconditional, all 9 loads in flight ----
        {
            uint4 v[9];
#pragma unroll
            for (int j = 0; j < 3; ++j)
#pragma unroll
                for (int k = 0; k < 3; ++k)
                    v[j * 3 + k] = LOADPX(j, k);
#pragma unroll
            for (int j = 0; j < 3; ++j)
#pragma unroll
                for (int k = 0; k < 3; ++k)
                    ACCUM(j, k, v[j * 3 + k]);
        }
        // ---- column strips k=3,4 (incl. corners), row strips j=3,4 ----
#pragma unroll
        for (int k = 3; k < 5; ++k) {
            if (WX[k] > 0.0f) {
                uint4 v[3];
#pragma unroll
                for (int j = 0; j < 3; ++j) v[j] = LOADPX(j, k);
#pragma unroll
                for (int j = 0; j < 3; ++j) ACCUM(j, k, v[j]);
#pragma unroll
                for (int j = 3; j < 5; ++j) {
                    if (WY[j] > 0.0f) { const uint4 c = LOADPX(j, k); ACCUM(j, k, c); }
                }
            }
        }
#pragma unroll
        for (int j = 3; j < 5; ++j) {
            if (WY[j] > 0.0f) {
                uint4 v[3];
#pragma unroll
                for (int k = 0; k < 3; ++k) v[k] = LOADPX(j, k);
#pragma unroll
                for (int k = 0; k < 3; ++k) ACCUM(j, k, v[k]);
            }
        }
#undef ACCUM
#undef LOADPX

        const float inv = (cnt > 0) ? (1.0f / (float)cnt) : 0.0f;
#pragma unroll
        for (int j = 0; j < 8; ++j)
            sout[(ch0 + j) * PP_ + bin] = acc[j] * inv;
    }

    __syncthreads();
    // out[n, g*32 : (g+1)*32, :, :] contiguous: 32*49 = 1568 floats
    float* outn = out + ((size_t)n * C_ + g * GC_) * PP_;
    for (int f = tid; f < GC_ * PP_; f += 256)
        __builtin_nontemporal_store(sout[f], &outn[f]);
}

extern "C" void kernel_launch(void* const* d_in, const int* in_sizes, int n_in,
                              void* d_out, int out_size, void* d_ws, size_t ws_size,
                              hipStream_t stream) {
    const float* feat  = (const float*)d_in[0];   // (2,256,96,96) f32
    const float* rois  = (const float*)d_in[1];   // (512,5)
    const float* trans = (const float*)d_in[2];   // (512,2,7,7)
    float* out = (float*)d_out;                   // (512,256,7,7) f32

    ushort* gp = (ushort*)d_ws;                   // bf16 group-planar, 9.4 MB
    dim3 tb(256);
    dim3 tg((HW_ / 32) * NGROUP_, 1, B_);         // g = blockIdx.x & 7
    nchw_to_gp_bf16<<<tg, tb, 0, stream>>>(feat, gp);
    dpsroi_pool8<<<NROIS_ * NGROUP_, 256, 0, stream>>>(gp, rois, trans, out);
}